// Round 11
// baseline (530.016 us; speedup 1.0000x reference)
//
#include <hip/hip_runtime.h>

// CLIP attention: B=32 S=577 E=1024 H=16 D=64
#define BB 32
#define SS 577
#define EE 1024
#define HH 16
#define DD 64
#define MROWS (BB * SS)   // 18464
#define SQP   640         // S padded to multiple of 64
#define NHEAD (BB * HH)   // 512

typedef __attribute__((ext_vector_type(8))) short short8;
typedef __attribute__((ext_vector_type(4))) float f32x4;
typedef __attribute__((ext_vector_type(16))) float f32x16;

__device__ __forceinline__ unsigned short f2bf(float x) {
  unsigned int u = __float_as_uint(x);
  u += 0x7fffu + ((u >> 16) & 1u);   // RNE
  return (unsigned short)(u >> 16);
}

__device__ __forceinline__ f32x4 mfma16(short8 a, short8 b, f32x4 c) {
  return __builtin_amdgcn_mfma_f32_16x16x32_bf16(a, b, c, 0, 0, 0);
}
__device__ __forceinline__ f32x16 mfma32(short8 a, short8 b, f32x16 c) {
  return __builtin_amdgcn_mfma_f32_32x32x16_bf16(a, b, c, 0, 0, 0);
}

typedef __attribute__((address_space(1))) unsigned int gu32;
typedef __attribute__((address_space(3))) unsigned int lu32;

__device__ __forceinline__ void gload_lds16(const void* g, void* l) {
  __builtin_amdgcn_global_load_lds((gu32*)g, (lu32*)l, 16, 0, 0);
}

__device__ __forceinline__ void bar() {
  asm volatile("" ::: "memory");
  __builtin_amdgcn_s_barrier();
  asm volatile("" ::: "memory");
}
#define FENCE() asm volatile("" ::: "memory")
#define VMCNT0() asm volatile("s_waitcnt vmcnt(0)" ::: "memory")
#define VMCNT4() asm volatile("s_waitcnt vmcnt(4)" ::: "memory")
#define VMCNT8() asm volatile("s_waitcnt vmcnt(8)" ::: "memory")
#define LGKM0()                                         \
  do {                                                  \
    asm volatile("s_waitcnt lgkmcnt(0)" ::: "memory");  \
    __builtin_amdgcn_sched_barrier(0);                  \
  } while (0)

// ---------------- conversions ----------------

__global__ __launch_bounds__(256) void convert_x(const float* __restrict__ X,
                                                 unsigned short* __restrict__ Xb) {
  size_t i = (size_t)blockIdx.x * 256 + threadIdx.x;  // 2,363,392 threads exactly
  const float4* src = (const float4*)X + i * 2;
  float4 a = src[0], b = src[1];
  uint4 o;
  o.x = (unsigned)f2bf(a.x) | ((unsigned)f2bf(a.y) << 16);
  o.y = (unsigned)f2bf(a.z) | ((unsigned)f2bf(a.w) << 16);
  o.z = (unsigned)f2bf(b.x) | ((unsigned)f2bf(b.y) << 16);
  o.w = (unsigned)f2bf(b.z) | ((unsigned)f2bf(b.w) << 16);
  ((uint4*)Xb)[i] = o;
}

__global__ __launch_bounds__(256) void convert_w(const float* __restrict__ qw,
                                                 const float* __restrict__ kw,
                                                 const float* __restrict__ vw,
                                                 const float* __restrict__ ow,
                                                 unsigned short* __restrict__ Wqkv,
                                                 unsigned short* __restrict__ Wo) {
  int i = blockIdx.x * 256 + threadIdx.x;  // 524,288 threads exactly
  if (i < 393216) {                        // Wqkv: 3072*1024 elems / 8
    int e = i * 8;
    int f = e >> 10, col = e & 1023;
    const float* src;
    float scale;
    if (f < 1024)      { src = qw + (size_t)f * 1024 + col;          scale = 0.125f; }
    else if (f < 2048) { src = kw + (size_t)(f - 1024) * 1024 + col; scale = 1.0f; }
    else               { src = vw + (size_t)(f - 2048) * 1024 + col; scale = 1.0f; }
    float4 a = ((const float4*)src)[0], b = ((const float4*)src)[1];
    uint4 o;
    o.x = (unsigned)f2bf(a.x * scale) | ((unsigned)f2bf(a.y * scale) << 16);
    o.y = (unsigned)f2bf(a.z * scale) | ((unsigned)f2bf(a.w * scale) << 16);
    o.z = (unsigned)f2bf(b.x * scale) | ((unsigned)f2bf(b.y * scale) << 16);
    o.w = (unsigned)f2bf(b.z * scale) | ((unsigned)f2bf(b.w * scale) << 16);
    ((uint4*)Wqkv)[i] = o;
  } else {
    int e = (i - 393216) * 8;
    float4 a = ((const float4*)(ow + e))[0], b = ((const float4*)(ow + e))[1];
    uint4 o;
    o.x = (unsigned)f2bf(a.x) | ((unsigned)f2bf(a.y) << 16);
    o.y = (unsigned)f2bf(a.z) | ((unsigned)f2bf(a.w) << 16);
    o.z = (unsigned)f2bf(b.x) | ((unsigned)f2bf(b.y) << 16);
    o.w = (unsigned)f2bf(b.z) | ((unsigned)f2bf(b.w) << 16);
    ((uint4*)Wo)[i - 393216] = o;
  }
}

__global__ __launch_bounds__(256) void bias_concat(const float* __restrict__ qb,
                                                   const float* __restrict__ kb,
                                                   const float* __restrict__ vb,
                                                   float* __restrict__ biasq) {
  int i = blockIdx.x * 256 + threadIdx.x;
  if (i >= 3072) return;
  float v;
  if (i < 1024)      v = 0.125f * qb[i];
  else if (i < 2048) v = kb[i - 1024];
  else               v = vb[i - 2048];
  biasq[i] = v;
}

// ---------------- QKV GEMM v3: 256x256 tile, BK=32, 4-buffer depth-3 pipeline ----------------
// 8 waves (2Mx4N), per-wave out 128x64, acc[8][4]. LDS 4 x (16K A + 16K B) = 128 KiB.
// Per step t: vmcnt(8) [drains stage(t), issued 3 steps ago -> latency fully covered],
// ONE barrier, issue stage(t+3), 12 ds_read_b128, lgkmcnt(0)+sched_barrier, 32 MFMA.
// 64B LDS rows are naturally bank-staggered for this read pattern -> no swizzle needed.
// Epilogue (identical to v2): Q linear; K stored with d^((s&7)<<3); Vt pos64-permuted
// then within-64 ^((d&7)<<3) -- the layouts attn3 consumes.

__global__ __launch_bounds__(512, 2) void gemm256_qkv(const unsigned short* __restrict__ A,
                                                      const unsigned short* __restrict__ Bw,
                                                      const float* __restrict__ bias,
                                                      unsigned short* __restrict__ Qb,
                                                      unsigned short* __restrict__ Kb,
                                                      unsigned short* __restrict__ Vtb) {
  __shared__ __align__(16) unsigned short Ab[4][256 * 32];
  __shared__ __align__(16) unsigned short Bb[4][256 * 32];
  const int tid = threadIdx.x;
  const int wave = tid >> 6, lane = tid & 63;
  const int c15 = lane & 15, hi4 = lane >> 4;
  const int wm = wave >> 2, wn = wave & 3;

  const int nwg = gridDim.x;
  const int q8 = nwg >> 3, r8 = nwg & 7;
  const int xcd = blockIdx.x & 7, idx8 = blockIdx.x >> 3;
  const int lid = (xcd < r8 ? xcd * (q8 + 1) : r8 * (q8 + 1) + (xcd - r8) * q8) + idx8;
  const int mtile = lid / 12, ntile = lid - mtile * 12;
  const int rowA0 = mtile * 256, rowB0 = ntile * 256;

  f32x4 acc[8][4];
#pragma unroll
  for (int i = 0; i < 8; i++)
#pragma unroll
    for (int j = 0; j < 4; j++) acc[i][j] = (f32x4){0.f, 0.f, 0.f, 0.f};

  // stage K-step (k0) into buffer buf: 2 gloads A + 2 gloads B per thread (32 KB total)
  auto stage = [&](int buf, int k0) {
#pragma unroll
    for (int u = 0; u < 2; u++) {
      int y = u * 8192 + tid * 16;
      int r = y >> 6;
      int row = rowA0 + r;
      if (row > MROWS - 1) row = MROWS - 1;  // M-pad clamp (mtile 72)
      gload_lds16(&A[(size_t)row * 1024 + k0 + ((y & 63) >> 1)],
                  &Ab[buf][u * 4096 + wave * 512]);
    }
#pragma unroll
    for (int u = 0; u < 2; u++) {
      int y = u * 8192 + tid * 16;
      int r = y >> 6;
      gload_lds16(&Bw[(size_t)(rowB0 + r) * 1024 + k0 + ((y & 63) >> 1)],
                  &Bb[buf][u * 4096 + wave * 512]);
    }
  };

  auto compute = [&](int buf) {
    short8 aF[8], bF[4];
#pragma unroll
    for (int ni = 0; ni < 4; ni++)
      bF[ni] = *(const short8*)((const char*)&Bb[buf][0] +
                                (wn * 64 + ni * 16 + c15) * 64 + hi4 * 16);
#pragma unroll
    for (int mi = 0; mi < 8; mi++)
      aF[mi] = *(const short8*)((const char*)&Ab[buf][0] +
                                (wm * 128 + mi * 16 + c15) * 64 + hi4 * 16);
    LGKM0();  // all LDS reads sampled before any later barrier can be crossed
    __builtin_amdgcn_s_setprio(1);
#pragma unroll
    for (int mi = 0; mi < 8; mi++)
#pragma unroll
      for (int ni = 0; ni < 4; ni++)
        acc[mi][ni] = mfma16(aF[mi], bF[ni], acc[mi][ni]);
    __builtin_amdgcn_s_setprio(0);
  };

  FENCE();
  stage(0, 0);
  FENCE();
  stage(1, 32);
  FENCE();
  stage(2, 64);
  FENCE();

#pragma unroll 1
  for (int t = 0; t <= 28; t++) {
    VMCNT8();                        // stage(t) landed (issued 3 steps ago); 8 newer in flight
    bar();                           // all waves' stage(t) landed; prev-step reads sampled
    stage((t + 3) & 3, (t + 3) * 32);
    compute(t & 3);
  }
  VMCNT8(); bar(); compute(29 & 3);  // outstanding: stage(29,30,31)=12 -> drains 29
  VMCNT4(); bar(); compute(30 & 3);  // outstanding: 8 -> drains 30
  VMCNT0(); bar(); compute(31 & 3);

  // epilogue: scatter Q,K [head][SQP][64]; Vt [head][64][SQP] (attn-swizzled layouts)
  float bv4[4];
  int f4[4];
#pragma unroll
  for (int ni = 0; ni < 4; ni++) {
    f4[ni] = rowB0 + wn * 64 + ni * 16 + c15;
    bv4[ni] = bias[f4[ni]];
  }
  const int tsel = (rowB0 + wn * 64) >> 10;
#pragma unroll
  for (int mi = 0; mi < 8; mi++) {
#pragma unroll
    for (int rr = 0; rr < 4; rr++) {
      int bs = rowA0 + wm * 128 + mi * 16 + hi4 * 4 + rr;
      if (bs >= MROWS) continue;
      int b = bs / SS, s = bs - b * SS;
      int ks = s & 63;
      int sp = (s & ~63) + ((ks >> 5) << 5) + (((ks >> 4) & 1) << 4) +
               (((ks >> 2) & 1) << 3) + ((ks & 3) | (((ks >> 3) & 1) << 2));
#pragma unroll
      for (int ni = 0; ni < 4; ni++) {
        int f = f4[ni];
        unsigned short bfv = f2bf(acc[mi][ni][rr] + bv4[ni]);
        int hd = f & 1023, h = hd >> 6, d = hd & 63;
        int head = (b << 4) + h;
        if (tsel == 0) {
          Qb[((size_t)head * SQP + s) * 64 + d] = bfv;
        } else if (tsel == 1) {
          int dsw = d ^ ((s & 7) << 3);  // attn K-LDS swizzle (baked into global layout)
          Kb[((size_t)head * SQP + s) * 64 + dsw] = bfv;
        } else {
          int spf = (sp & ~63) | ((sp & 63) ^ ((d & 7) << 3));  // attn V-LDS swizzle
          Vtb[((size_t)head * 64 + d) * SQP + spf] = bfv;
        }
      }
    }
  }
}

// ---------------- O-proj GEMM (unchanged 128x128 m97-structure) ----------------

template <int NX>
__global__ __launch_bounds__(256) void gemm_bt(const unsigned short* __restrict__ A,
                                               const unsigned short* __restrict__ Bw,
                                               const float* __restrict__ bias,
                                               float* __restrict__ outF) {
  __shared__ __align__(16) unsigned short lds[2][2][128 * 32];
  const int tid = threadIdx.x;
  const int wave = tid >> 6, lane = tid & 63;
  const int c = lane & 15, g = lane >> 4;
  const int wm = wave >> 1, wn = wave & 1;
  const int chunk = gridDim.x >> 3;
  const int lid = (blockIdx.x & 7) * chunk + (blockIdx.x >> 3);
  const int ntile = lid % NX, mtile = lid / NX;
  const int rowA0 = mtile * 128, rowB0 = ntile * 128;

  f32x4 acc[4][4];
#pragma unroll
  for (int i = 0; i < 4; i++)
#pragma unroll
    for (int j = 0; j < 4; j++) acc[i][j] = (f32x4){0.f, 0.f, 0.f, 0.f};

  auto stage = [&](int bi, int k0) {
#pragma unroll
    for (int j = 0; j < 2; j++) {
      int idx = j * 256 + tid;
      int r = idx >> 2, blk = idx & 3;
      gload_lds16(&A[(size_t)(rowA0 + r) * 1024 + k0 + blk * 8],
                  &lds[bi][0][(j * 256 + wave * 64) * 8]);
    }
#pragma unroll
    for (int j = 0; j < 2; j++) {
      int idx = j * 256 + tid;
      int r = idx >> 2, blk = idx & 3;
      gload_lds16(&Bw[(size_t)(rowB0 + r) * 1024 + k0 + blk * 8],
                  &lds[bi][1][(j * 256 + wave * 64) * 8]);
    }
  };

  auto compute = [&](int bi) {
    const unsigned short* As = &lds[bi][0][0];
    const unsigned short* Bs = &lds[bi][1][0];
    short8 af[4], bf_[4];
#pragma unroll
    for (int i = 0; i < 4; i++)
      af[i] = *(const short8*)&As[(wm * 64 + i * 16 + c) * 32 + g * 8];
#pragma unroll
    for (int j = 0; j < 4; j++)
      bf_[j] = *(const short8*)&Bs[(wn * 64 + j * 16 + c) * 32 + g * 8];
#pragma unroll
    for (int i = 0; i < 4; i++)
#pragma unroll
      for (int j = 0; j < 4; j++) acc[i][j] = mfma16(af[i], bf_[j], acc[i][j]);
  };

  stage(0, 0);
  __syncthreads();
  int cur = 0;
  for (int t = 0; t < 31; t++) {
    stage(cur ^ 1, (t + 1) * 32);
    compute(cur);
    __syncthreads();
    cur ^= 1;
  }
  compute(cur);

#pragma unroll
  for (int j = 0; j < 4; j++) {
    int f = rowB0 + wn * 64 + j * 16 + c;
    float bv = bias[f];
#pragma unroll
    for (int i = 0; i < 4; i++) {
      int rb = rowA0 + wm * 64 + i * 16 + g * 4;
#pragma unroll
      for (int r = 0; r < 4; r++) {
        int bs = rb + r;
        if (bs >= MROWS) continue;
        outF[(size_t)bs * 1024 + f] = acc[i][j][r] + bv;
      }
    }
  }
}

// ---------------- flash attention: LDS-staged K/V, depth-2, counted vmcnt (unchanged) ----------------

__global__ __launch_bounds__(256) void attn3(const unsigned short* __restrict__ Q,
                                             const unsigned short* __restrict__ K,
                                             const unsigned short* __restrict__ Vt,
                                             unsigned short* __restrict__ O) {
  __shared__ __align__(16) char KL[2][8192];
  __shared__ __align__(16) char VL[2][8192];
  const int chunk = gridDim.x >> 3;           // 320
  const int lid = (blockIdx.x & 7) * chunk + (blockIdx.x >> 3);
  const int head = lid / 5, qb = lid - head * 5;
  const int tid = threadIdx.x;
  const int wv = tid >> 6, lane = tid & 63;
  const int ln31 = lane & 31, hi = lane >> 5;
  const int q0 = qb * 128 + wv * 32;          // may be >= SS for tail waves: outputs guarded

  const unsigned short* Qh = Q + (size_t)head * SQP * 64;
  const char* Kg = (const char*)(K + (size_t)head * SQP * 64);
  const char* Vg = (const char*)(Vt + (size_t)head * 64 * SQP);

  auto stage = [&](int t, int sb) {
    const char* kt = Kg + (size_t)t * 8192;
    const char* vt = Vg + (size_t)t * 128;
#pragma unroll
    for (int i = 0; i < 2; i++) {
      int idx = i * 256 + tid;
      gload_lds16(kt + (size_t)idx * 16, &KL[sb][(i * 256 + wv * 64) * 16]);
    }
#pragma unroll
    for (int i = 0; i < 2; i++) {
      int idx = i * 256 + tid;
      gload_lds16(vt + (size_t)(idx >> 3) * 1280 + ((idx & 7) << 4),
                  &VL[sb][(i * 256 + wv * 64) * 16]);
    }
  };

  short8 qf[4];
#pragma unroll
  for (int dc = 0; dc < 4; dc++)
    qf[dc] = *(const short8*)&Qh[(size_t)(q0 + ln31) * 64 + dc * 16 + hi * 8];

  f32x16 oacc0, oacc1;
#pragma unroll
  for (int r = 0; r < 16; r++) { oacc0[r] = 0.f; oacc1[r] = 0.f; }
  float lsum = 0.f;

  auto comp = [&](int sb, bool mask) {
    const char* Kl = &KL[sb][0];
    const char* Vl = &VL[sb][0];
    short8 kv0[4], kv1[4];
#pragma unroll
    for (int dc = 0; dc < 4; dc++) {
      int cb = (dc * 32 + hi * 16) ^ ((ln31 & 7) << 4);
      kv0[dc] = *(const short8*)(Kl + ln31 * 128 + cb);
      kv1[dc] = *(const short8*)(Kl + (32 + ln31) * 128 + cb);
    }
    LGKM0();  // K reads sampled before barrier can be crossed
    f32x16 s0, s1;
#pragma unroll
    for (int r = 0; r < 16; r++) { s0[r] = 0.f; s1[r] = 0.f; }
#pragma unroll
    for (int dc = 0; dc < 4; dc++) {
      s0 = mfma32(kv0[dc], qf[dc], s0);
      s1 = mfma32(kv1[dc], qf[dc], s1);
    }
    if (mask) {  // keys 576..639: only 576 valid
#pragma unroll
      for (int r = 0; r < 16; r++) {
        int kk = 576 + ((r & 3) + 8 * (r >> 2) + 4 * hi);
        if (kk >= SS) s0[r] = -1e30f;
        s1[r] = -1e30f;
      }
    }
    float rs = 0.f;
#pragma unroll
    for (int r = 0; r < 16; r++) {
      s0[r] = __expf(s0[r]);
      s1[r] = __expf(s1[r]);
      rs += s0[r] + s1[r];
    }
    rs += __shfl_xor(rs, 32);
    lsum += rs;

    union { short8 v; unsigned u[4]; } pb00, pb01, pb10, pb11;
#pragma unroll
    for (int jj = 0; jj < 4; jj++) {
      pb00.u[jj] = __builtin_amdgcn_perm(__float_as_uint(s0[2 * jj + 1]) + 0x8000u,
                                         __float_as_uint(s0[2 * jj]) + 0x8000u, 0x07060302u);
      pb01.u[jj] = __builtin_amdgcn_perm(__float_as_uint(s0[8 + 2 * jj + 1]) + 0x8000u,
                                         __float_as_uint(s0[8 + 2 * jj]) + 0x8000u, 0x07060302u);
      pb10.u[jj] = __builtin_amdgcn_perm(__float_as_uint(s1[2 * jj + 1]) + 0x8000u,
                                         __float_as_uint(s1[2 * jj]) + 0x8000u, 0x07060302u);
      pb11.u[jj] = __builtin_amdgcn_perm(__float_as_uint(s1[8 + 2 * jj + 1]) + 0x8000u,
                                         __float_as_uint(s1[8 + 2 * jj]) + 0x8000u, 0x07060302u);
    }
    short8 vf[8];
#pragma unroll
    for (int ks = 0; ks < 4; ks++) {
      int cb0 = (hi * 16 + ks * 32) ^ ((ln31 & 7) << 4);
      vf[ks]     = *(const short8*)(Vl + ln31 * 128 + cb0);
      vf[4 + ks] = *(const short8*)(Vl + (32 + ln31) * 128 + cb0);
    }
    LGKM0();  // V reads sampled before barrier can be crossed
    oacc0 = mfma32(vf[0], pb00.v, oacc0);
    oacc0 = mfma32(vf[1], pb01.v, oacc0);
    oacc0 = mfma32(vf[2], pb10.v, oacc0);
    oacc0 = mfma32(vf[3], pb11.v, oacc0);
    oacc1 = mfma32(vf[4], pb00.v, oacc1);
    oacc1 = mfma32(vf[5], pb01.v, oacc1);
    oacc1 = mfma32(vf[6], pb10.v, oacc1);
    oacc1 = mfma32(vf[7], pb11.v, oacc1);
  };

  FENCE();       // pin VMEM issue order: qf, stage(0), stage(1)
  stage(0, 0);
  FENCE();
  stage(1, 1);
  FENCE();
#pragma unroll 1
  for (int t = 0; t < 9; t++) {
    VMCNT4();   // own stage(t) loads landed (stage(t+1) still in flight)
    bar();      // everyone's stage(t) landed
    comp(t & 1, false);
    bar();      // all waves done sampling buf t&1 (LGKM0 inside comp guarantees)
    if (t < 8) stage(t + 2, t & 1);
  }
  VMCNT0();
  bar();
  comp(1, true);  // tile 9

  const float inv = 1.f / lsum;
  const int q = q0 + ln31;
  if (q < SS) {
    const size_t rowb = ((size_t)(head >> 4) * SS + q) * 1024 + (head & 15) * 64;
#pragma unroll
    for (int jj = 0; jj < 8; jj++) {
      int rr = 2 * jj;
      int d = (rr & 3) + 8 * (rr >> 2) + 4 * hi;
      unsigned u0 = (unsigned)f2bf(oacc0[rr] * inv) | ((unsigned)f2bf(oacc0[rr + 1] * inv) << 16);
      unsigned u1 = (unsigned)f2bf(oacc1[rr] * inv) | ((unsigned)f2bf(oacc1[rr + 1] * inv) << 16);
      *(unsigned*)&O[rowb + d] = u0;
      *(unsigned*)&O[rowb + 32 + d] = u1;
    }
  }
}

// ---------------- launch ----------------

extern "C" void kernel_launch(void* const* d_in, const int* in_sizes, int n_in,
                              void* d_out, int out_size, void* d_ws, size_t ws_size,
                              hipStream_t stream) {
  const float* hs = (const float*)d_in[0];
  const float* qw = (const float*)d_in[1];
  const float* qb = (const float*)d_in[2];
  const float* kw = (const float*)d_in[3];
  const float* kb = (const float*)d_in[4];
  const float* vw = (const float*)d_in[5];
  const float* vb = (const float*)d_in[6];
  const float* ow = (const float*)d_in[7];
  const float* ob = (const float*)d_in[8];

  char* ws = (char*)d_ws;
  unsigned short* Wqkv = (unsigned short*)(ws);               //  6,291,456 B
  unsigned short* Wo   = (unsigned short*)(ws + 6291456);     //  2,097,152 B
  float*          bq   = (float*)(ws + 8388608);              //     12,288 B
  unsigned short* Xb   = (unsigned short*)(ws + 8401920);     // 38,010,880 B (18560 rows; reused as attn O)
  unsigned short* Qb   = (unsigned short*)(ws + 46412800);    // 41,943,040 B
  unsigned short* Kb   = (unsigned short*)(ws + 88355840);    // 41,943,040 B
  unsigned short* Vtb  = (unsigned short*)(ws + 130298880);   // 41,943,040 B -> total 172,241,920

  convert_x<<<9232, 256, 0, stream>>>(hs, Xb);
  convert_w<<<2048, 256, 0, stream>>>(qw, kw, vw, ow, Wqkv, Wo);
  bias_concat<<<12, 256, 0, stream>>>(qb, kb, vb, bq);
  gemm256_qkv<<<876, 512, 0, stream>>>(Xb, Wqkv, bq, Qb, Kb, Vtb);  // 73 x 12 tiles
  attn3<<<2560, 256, 0, stream>>>(Qb, Kb, Vtb, Xb);
  gemm_bt<8><<<1160, 256, 0, stream>>>(Xb, Wo, ob, (float*)d_out);
}